// Round 11
// baseline (1382.328 us; speedup 1.0000x reference)
//
#include <hip/hip_runtime.h>
#include <hip/hip_bf16.h>
#include <hip/hip_fp16.h>

// ---- problem constants ----
#define TOK 8192      // 4*2048 tokens
#define HD 2048      // hidden
#define ID 4096      // intermediate
#define NE 8         // experts
#define NPAIR (TOK*2) // token-expert pairs (TOPK=2)
#define BM 128
#define MAXMT (NPAIR/BM + NE)   // 136 worst-case M-tiles
#define PPAD (NPAIR + NE*BM)    // 17408 worst-case padded rows (136*128)

typedef unsigned short u16;
typedef unsigned int u32;
typedef __attribute__((ext_vector_type(4))) float f32x4;
typedef __attribute__((ext_vector_type(4))) int   i32x4;
typedef u16 u16x8 __attribute__((ext_vector_type(8)));
typedef u16 u16x4 __attribute__((ext_vector_type(4)));

__device__ __forceinline__ u16 f2h(float f) {
    __half h = __float2half_rn(f);
    return *reinterpret_cast<u16*>(&h);
}

// K-tiled layout for all staged fp16 matrices except gathered xh:
//   element(r, k) -> (r>>7)*(K_TOTAL*128) + (k>>6)*8192 + (r&127)*64 + (k&63)
// Each (panel, kt) slice is a contiguous 16 KB burst (128 rows x 64 k).

// ---------------- router (+ fused x fp32->fp16 cast) ----------------
__global__ void router_kernel(const float* __restrict__ x, const float* __restrict__ wg,
                              u16* __restrict__ xh,
                              int* __restrict__ top_e, float* __restrict__ top_w,
                              int* __restrict__ counts) {
    int t = blockIdx.x * 4 + (threadIdx.x >> 6);
    int l = threadIdx.x & 63;
    const float* xr = x + (size_t)t * HD;
    u16* xo = xh + (size_t)t * HD;
    float acc[NE];
#pragma unroll
    for (int e = 0; e < NE; ++e) acc[e] = 0.f;
    for (int h0 = 0; h0 < HD; h0 += 64) {
        int h = h0 + l;
        float xv = xr[h];
        xo[h] = f2h(xv);
        const f32x4* wr = (const f32x4*)(wg + (size_t)h * NE);
        f32x4 w0 = wr[0], w1v = wr[1];
#pragma unroll
        for (int i = 0; i < 4; ++i) { acc[i] += xv * w0[i]; acc[4 + i] += xv * w1v[i]; }
    }
#pragma unroll
    for (int e = 0; e < NE; ++e) {
        float v = acc[e];
        for (int s = 32; s >= 1; s >>= 1) v += __shfl_xor(v, s);
        acc[e] = v;
    }
    if (l == 0) {
        float li[NE], mx = -1e30f;
#pragma unroll
        for (int e = 0; e < NE; ++e) { li[e] = 30.f * tanhf(acc[e] * (1.f / 30.f)); mx = fmaxf(mx, li[e]); }
        float p[NE], se = 0.f;
#pragma unroll
        for (int e = 0; e < NE; ++e) { p[e] = expf(li[e] - mx); se += p[e]; }
        float inv = 1.f / se;
        int i1 = 0; float p1 = p[0];
#pragma unroll
        for (int e = 1; e < NE; ++e) if (p[e] > p1) { p1 = p[e]; i1 = e; }
        int i2 = -1; float p2 = -1e30f;
#pragma unroll
        for (int e = 0; e < NE; ++e) if (e != i1 && p[e] > p2) { p2 = p[e]; i2 = e; }
        top_e[t * 2] = i1; top_e[t * 2 + 1] = i2;
        top_w[t * 2] = p1 * inv; top_w[t * 2 + 1] = p2 * inv;
        atomicAdd(&counts[i1], 1); atomicAdd(&counts[i2], 1);
    }
}

// ---------------- prep: w1/w3 fp32 [H][I] -> interleaved fp16 wcat, K-tiled ----------------
__global__ __launch_bounds__(256) void prep_w13_kernel(const float* __restrict__ w1,
                                                       const float* __restrict__ w3,
                                                       u16* __restrict__ wcat) {
    __shared__ u16 tile[64][68];   // [n_local][k_local]
    const int k0 = blockIdx.x * 64, n0 = blockIdx.y * 64;
    const int e = blockIdx.z >> 1, which = blockIdx.z & 1;
    const float* src = (which ? w3 : w1) + (size_t)e * HD * ID;
    u16* dst = wcat + (size_t)e * 2 * ID * HD;
    const int tid = threadIdx.x, r = tid >> 4, c4 = (tid & 15) * 4;
#pragma unroll
    for (int i = 0; i < 4; ++i) {
        int k = k0 + r + 16 * i;
        f32x4 v = *(const f32x4*)(src + (size_t)k * ID + n0 + c4);
#pragma unroll
        for (int j = 0; j < 4; ++j) tile[c4 + j][r + 16 * i] = f2h(v[j]);
    }
    __syncthreads();
#pragma unroll
    for (int i = 0; i < 4; ++i) {
        int nl = r + 16 * i;
        int n = n0 + nl;
        int wr = ((n >> 4) << 5) | (which << 4) | (n & 15);
        u16x4 o;
#pragma unroll
        for (int j = 0; j < 4; ++j) o[j] = tile[nl][c4 + j];
        size_t off = (size_t)(wr >> 7) * (HD * 128) + (size_t)(k0 >> 6) * 8192
                   + (wr & 127) * 64 + c4;
        *(u16x4*)(dst + off) = o;
    }
}

// ---------------- prep: w2 fp32 [I][H] -> fp16 w2t [H-rows][I-k], K-tiled ----------------
__global__ __launch_bounds__(256) void prep_w2_kernel(const float* __restrict__ w2,
                                                      u16* __restrict__ w2t) {
    __shared__ u16 tile[64][68];
    const int k0 = blockIdx.x * 64, n0 = blockIdx.y * 64;
    const int e = blockIdx.z;
    const float* src = w2 + (size_t)e * ID * HD;
    u16* dst = w2t + (size_t)e * ID * HD;
    const int tid = threadIdx.x, r = tid >> 4, c4 = (tid & 15) * 4;
#pragma unroll
    for (int i = 0; i < 4; ++i) {
        int k = k0 + r + 16 * i;
        f32x4 v = *(const f32x4*)(src + (size_t)k * HD + n0 + c4);
#pragma unroll
        for (int j = 0; j < 4; ++j) tile[c4 + j][r + 16 * i] = f2h(v[j]);
    }
    __syncthreads();
#pragma unroll
    for (int i = 0; i < 4; ++i) {
        int nl = r + 16 * i;
        int rr = n0 + nl;
        u16x4 o;
#pragma unroll
        for (int j = 0; j < 4; ++j) o[j] = tile[nl][c4 + j];
        size_t off = (size_t)(rr >> 7) * (ID * 128) + (size_t)(k0 >> 6) * 8192
                   + (rr & 127) * 64 + c4;
        *(u16x4*)(dst + off) = o;
    }
}

// ---------------- offsets + M-tile table (1 thread) ----------------
__global__ void offsets_kernel(const int* __restrict__ counts, int* __restrict__ offs,
                               int* __restrict__ mt_e, int* __restrict__ mt_r0,
                               int* __restrict__ nmt) {
    if (threadIdx.x != 0) return;
    int off = 0, n = 0;
    for (int e = 0; e < NE; ++e) {
        offs[e] = off;
        int c = counts[e];
        int nt = (c + BM - 1) >> 7;
        for (int j = 0; j < nt; ++j) { mt_e[n] = e; mt_r0[n] = off + j * BM; ++n; }
        off += nt * BM;
    }
    offs[NE] = off;
    *nmt = n;
}

// ---------------- deterministic per-expert compaction ----------------
// pair_tok2[pos] = token*2 + slot; pads = -2
__global__ void scatter_kernel(const int* __restrict__ top_e, const float* __restrict__ top_w,
                               const int* __restrict__ counts, const int* __restrict__ offs,
                               int* __restrict__ pair_tok2, float* __restrict__ pair_w) {
    const int e = blockIdx.x;
    const int tid = threadIdx.x;
    __shared__ int sc[256];
    int base = offs[e];
    for (int start = 0; start < TOK; start += 256) {
        int tk = start + tid;
        int m = 0; float w = 0.f; int slot = 0;
        int e0 = top_e[tk * 2], e1 = top_e[tk * 2 + 1];
        if (e0 == e) { m = 1; w = top_w[tk * 2]; slot = 0; }
        else if (e1 == e) { m = 1; w = top_w[tk * 2 + 1]; slot = 1; }
        sc[tid] = m;
        __syncthreads();
        for (int s = 1; s < 256; s <<= 1) {
            int v = (tid >= s) ? sc[tid - s] : 0;
            __syncthreads();
            sc[tid] += v;
            __syncthreads();
        }
        if (m) { int pos = base + sc[tid] - 1; pair_tok2[pos] = tk * 2 + slot; pair_w[pos] = w; }
        base += sc[255];
        __syncthreads();
    }
    int cnt = counts[e];
    int padded = (cnt + BM - 1) & ~(BM - 1);
    for (int r = cnt + tid; r < padded; r += 256) {
        pair_tok2[offs[e] + r] = -2;
        pair_w[offs[e] + r] = 0.f;
    }
}

// ---------------- GEMM1: h = silu(x@w1) * (x@w3), m97 structure, fp16 MFMA ----------------
// Split into 2 dispatches (kby = 0 / 32) so gemm2 becomes visible in profile top-5.
// Grid per dispatch: 72 padded clusters x 64 = 4608 blocks; C >= 68 early-exits
// (keeps all 136 mt covered: mtc = C>>2 in [0,17), byc = C&3 in [0,4)).
__global__ __launch_bounds__(256, 3) void gemm1_kernel(
    const u16* __restrict__ xh, const u16* __restrict__ wcat,
    const int* __restrict__ pair_tok2, const int* __restrict__ mt_e,
    const int* __restrict__ mt_r0, const int* __restrict__ nmt,
    u16* __restrict__ hb, int kby) {
    int p = blockIdx.x;
    int x = p & 7, j = p >> 3, c = j >> 6, s = j & 63;
    int C = c * 8 + x;                 // [0,72)
    if (C >= 68) return;
    int mt = (C >> 2) * 8 + (s >> 3);  // mt-major cluster order
    int by = kby + (C & 3) * 8 + (s & 7);
    if (mt >= *nmt) return;
    const int e = mt_e[mt], row0 = mt_r0[mt];
    const int tid = threadIdx.x, lane = tid & 63, wv = tid >> 6;
    const int wm = wv >> 1, wn = wv & 1;

    __shared__ u16 sA[128 * 64];
    __shared__ u16 sB[128 * 64];

    const u16* asrc[4];
    const u16* bsrc[4];
#pragma unroll
    for (int i = 0; i < 4; ++i) {
        int rl = i * 32 + (tid >> 3);
        int kbs = ((tid & 7) * 16) ^ ((rl & 7) << 4);      // byte offset, pre-swizzled
        int pt2 = pair_tok2[row0 + rl];
        int tok = pt2 < 0 ? 0 : (pt2 >> 1);
        asrc[i] = xh + (size_t)tok * HD + (kbs >> 1);
        bsrc[i] = wcat + (size_t)e * 2 * ID * HD + (size_t)by * (HD * 128)
                + rl * 64 + (kbs >> 1);
    }

    f32x4 acc[4][4];
#pragma unroll
    for (int a = 0; a < 4; ++a)
#pragma unroll
        for (int b = 0; b < 4; ++b) acc[a][b] = (f32x4)0.f;

    for (int kt = 0; kt < HD / 64; ++kt) {
#pragma unroll
        for (int i = 0; i < 4; ++i) {
            __builtin_amdgcn_global_load_lds(
                (const __attribute__((address_space(1))) void*)asrc[i],
                (__attribute__((address_space(3))) void*)(sA + i * 2048 + wv * 512), 16, 0, 0);
            asrc[i] += 64;
        }
#pragma unroll
        for (int i = 0; i < 4; ++i) {
            __builtin_amdgcn_global_load_lds(
                (const __attribute__((address_space(1))) void*)bsrc[i],
                (__attribute__((address_space(3))) void*)(sB + i * 2048 + wv * 512), 16, 0, 0);
            bsrc[i] += 8192;
        }
        __syncthreads();
#pragma unroll
        for (int ks = 0; ks < 2; ++ks) {
            i32x4 a[4], b[4];
#pragma unroll
            for (int mf = 0; mf < 4; ++mf) {
                int rr = wm * 64 + mf * 16 + (lane & 15);
                int lb = ((lane >> 4) * 16 + ks * 64) ^ ((rr & 7) << 4);
                a[mf] = *(const i32x4*)((const char*)sA + rr * 128 + lb);
            }
#pragma unroll
            for (int nf = 0; nf < 4; ++nf) {
                int nn = wn * 64 + nf * 16 + (lane & 15);
                int lb = ((lane >> 4) * 16 + ks * 64) ^ ((nn & 7) << 4);
                b[nf] = *(const i32x4*)((const char*)sB + nn * 128 + lb);
            }
#pragma unroll
            for (int nf = 0; nf < 4; ++nf)
#pragma unroll
                for (int mf = 0; mf < 4; ++mf)
                    asm("v_mfma_f32_16x16x32_f16 %0, %1, %2, %0" : "+v"(acc[mf][nf]) : "v"(a[mf]), "v"(b[nf]));
        }
        __syncthreads();
    }

    // epilogue -> K-tiled hb: col = by*64 + wn*32 + np*16 + l15, panel-k index = by
#pragma unroll
    for (int mf = 0; mf < 4; ++mf) {
#pragma unroll
        for (int j2 = 0; j2 < 4; ++j2) {
            int rr = row0 + wm * 64 + mf * 16 + (lane >> 4) * 4 + j2;
            u16* hp_ = hb + (size_t)(rr >> 7) * (ID * 128) + (size_t)by * 8192
                     + (rr & 127) * 64 + wn * 32 + (lane & 15);
#pragma unroll
            for (int np = 0; np < 2; ++np) {
                float g = acc[mf][2 * np][j2], u = acc[mf][2 * np + 1][j2];
                float sgl = g / (1.f + expf(-g));
                hp_[np * 16] = f2h(sgl * u);
            }
        }
    }
}

// ---------------- GEMM2: ob[tok*2+slot] = (h@w2t) * weight (plain stores) ----------------
// A (hb) and B (w2t) both K-tiled -> all stages are contiguous 16 KB bursts.
__global__ __launch_bounds__(256, 3) void gemm2_kernel(
    const u16* __restrict__ hb, const u16* __restrict__ w2t,
    const int* __restrict__ pair_tok2, const float* __restrict__ pair_w,
    const int* __restrict__ mt_e, const int* __restrict__ mt_r0, const int* __restrict__ nmt,
    float* __restrict__ ob) {
    int p = blockIdx.x;
    int x = p & 7, j = p >> 3, c = j >> 6, s = j & 63;
    int C = c * 8 + x;                 // [0,40)
    int mt = C * 4 + (s >> 4);         // [0,160), padded
    int by = s & 15;                   // [0,16)
    if (mt >= *nmt) return;
    const int e = mt_e[mt], row0 = mt_r0[mt];
    const int tid = threadIdx.x, lane = tid & 63, wv = tid >> 6;
    const int wm = wv >> 1, wn = wv & 1;

    __shared__ u16 sA[128 * 64];
    __shared__ u16 sB[128 * 64];

    const u16* asrc[4];
    const u16* bsrc[4];
#pragma unroll
    for (int i = 0; i < 4; ++i) {
        int rl = i * 32 + (tid >> 3);
        int kbs = ((tid & 7) * 16) ^ ((rl & 7) << 4);
        asrc[i] = hb + (size_t)(row0 >> 7) * (ID * 128) + rl * 64 + (kbs >> 1);
        bsrc[i] = w2t + (size_t)e * HD * ID + (size_t)by * (ID * 128) + rl * 64 + (kbs >> 1);
    }

    f32x4 acc[4][4];
#pragma unroll
    for (int a = 0; a < 4; ++a)
#pragma unroll
        for (int b = 0; b < 4; ++b) acc[a][b] = (f32x4)0.f;

    for (int kt = 0; kt < ID / 64; ++kt) {
#pragma unroll
        for (int i = 0; i < 4; ++i) {
            __builtin_amdgcn_global_load_lds(
                (const __attribute__((address_space(1))) void*)asrc[i],
                (__attribute__((address_space(3))) void*)(sA + i * 2048 + wv * 512), 16, 0, 0);
            asrc[i] += 8192;
        }
#pragma unroll
        for (int i = 0; i < 4; ++i) {
            __builtin_amdgcn_global_load_lds(
                (const __attribute__((address_space(1))) void*)bsrc[i],
                (__attribute__((address_space(3))) void*)(sB + i * 2048 + wv * 512), 16, 0, 0);
            bsrc[i] += 8192;
        }
        __syncthreads();
#pragma unroll
        for (int ks = 0; ks < 2; ++ks) {
            i32x4 a[4], b[4];
#pragma unroll
            for (int mf = 0; mf < 4; ++mf) {
                int rr = wm * 64 + mf * 16 + (lane & 15);
                int lb = ((lane >> 4) * 16 + ks * 64) ^ ((rr & 7) << 4);
                a[mf] = *(const i32x4*)((const char*)sA + rr * 128 + lb);
            }
#pragma unroll
            for (int nf = 0; nf < 4; ++nf) {
                int nn = wn * 64 + nf * 16 + (lane & 15);
                int lb = ((lane >> 4) * 16 + ks * 64) ^ ((nn & 7) << 4);
                b[nf] = *(const i32x4*)((const char*)sB + nn * 128 + lb);
            }
#pragma unroll
            for (int nf = 0; nf < 4; ++nf)
#pragma unroll
                for (int mf = 0; mf < 4; ++mf)
                    asm("v_mfma_f32_16x16x32_f16 %0, %1, %2, %0" : "+v"(acc[mf][nf]) : "v"(a[mf]), "v"(b[nf]));
        }
        __syncthreads();
    }

#pragma unroll
    for (int mf = 0; mf < 4; ++mf) {
#pragma unroll
        for (int j2 = 0; j2 < 4; ++j2) {
            int rr = row0 + wm * 64 + mf * 16 + (lane >> 4) * 4 + j2;
            int pt2 = pair_tok2[rr];
            float wt = pair_w[rr];
            if (pt2 >= 0) {
                float* op = ob + (size_t)pt2 * HD + by * 128 + wn * 64 + (lane & 15);
#pragma unroll
                for (int nf = 0; nf < 4; ++nf) {
                    op[nf * 16] = acc[mf][nf][j2] * wt;
                }
            }
        }
    }
}

// ---------------- combine: out[t] = ob[2t] + ob[2t+1] ----------------
__global__ __launch_bounds__(256) void combine_kernel(const float* __restrict__ ob,
                                                      float* __restrict__ out) {
    int t = blockIdx.x;
    const f32x4* r0 = (const f32x4*)(ob + (size_t)(2 * t) * HD);
    const f32x4* r1 = (const f32x4*)(ob + (size_t)(2 * t + 1) * HD);
    f32x4* o = (f32x4*)(out + (size_t)t * HD);
#pragma unroll
    for (int i = 0; i < 2; ++i) {
        int idx = threadIdx.x + i * 256;
        o[idx] = r0[idx] + r1[idx];
    }
}

extern "C" void kernel_launch(void* const* d_in, const int* in_sizes, int n_in,
                              void* d_out, int out_size, void* d_ws, size_t ws_size,
                              hipStream_t stream) {
    (void)in_sizes; (void)n_in; (void)out_size;
    const float* x  = (const float*)d_in[0];
    const float* wg = (const float*)d_in[1];
    const float* w1 = (const float*)d_in[2];
    const float* w3 = (const float*)d_in[3];
    const float* w2 = (const float*)d_in[4];
    float* out = (float*)d_out;

    char* ws = (char*)d_ws;
    size_t off = 0;
    auto alloc = [&](size_t bytes) -> void* {
        void* p = ws + off;
        off = (off + bytes + 255) & ~(size_t)255;
        return p;
    };
    u16* xh          = (u16*)alloc((size_t)TOK * HD * 2);
    u16* hb          = (u16*)alloc((size_t)PPAD * ID * 2);
    u16* wcat        = (u16*)alloc((size_t)NE * 2 * ID * HD * 2);  // w13 fp16
    float* ob        = (float*)wcat;   // aliases wcat 1st half (dead after gemm1)
    int* pair_tok2   = (int*)alloc((size_t)PPAD * 4);
    float* pair_w    = (float*)alloc((size_t)PPAD * 4);
    int* top_e       = (int*)alloc((size_t)TOK * 2 * 4);
    float* top_w     = (float*)alloc((size_t)TOK * 2 * 4);
    int* counts      = (int*)alloc(64);
    int* offs        = (int*)alloc(64);
    int* mt_e        = (int*)alloc((size_t)MAXMT * 4);
    int* mt_r0       = (int*)alloc((size_t)MAXMT * 4);
    int* nmt         = (int*)alloc(64);

    // plan A: separate w2t buffer -> prep_w2 can run BEFORE gemm1 so hb stays
    // L3-warm between gemm1 writes and gemm2 reads. Fallback B: alias wcat 2nd
    // half (R10 order). Decision is deterministic (ws_size fixed per run).
    size_t w2t_bytes = (size_t)NE * ID * HD * 2;
    bool planA = (off + w2t_bytes) <= ws_size;
    u16* w2t = planA ? (u16*)alloc(w2t_bytes)
                     : wcat + (size_t)NE * ID * HD;

    hipMemsetAsync(counts, 0, 64, stream);

    router_kernel<<<TOK / 4, 256, 0, stream>>>(x, wg, xh, top_e, top_w, counts);
    offsets_kernel<<<1, 64, 0, stream>>>(counts, offs, mt_e, mt_r0, nmt);
    scatter_kernel<<<NE, 256, 0, stream>>>(top_e, top_w, counts, offs, pair_tok2, pair_w);
    prep_w13_kernel<<<dim3(HD / 64, ID / 64, NE * 2), 256, 0, stream>>>(w1, w3, wcat);
    if (planA)
        prep_w2_kernel<<<dim3(ID / 64, HD / 64, NE), 256, 0, stream>>>(w2, w2t);
    // gemm1 split into two by-halves (diagnostic: exposes gemm2 in profile top-5)
    gemm1_kernel<<<4608, 256, 0, stream>>>(xh, wcat, pair_tok2, mt_e, mt_r0, nmt, hb, 0);
    gemm1_kernel<<<4608, 256, 0, stream>>>(xh, wcat, pair_tok2, mt_e, mt_r0, nmt, hb, 32);
    if (!planA)
        prep_w2_kernel<<<dim3(ID / 64, HD / 64, NE), 256, 0, stream>>>(w2, w2t);
    // gemm2: mt padded to 160 x 16 by, XCD-clustered (4mt x 16by clusters, 40 clusters)
    gemm2_kernel<<<160 * (HD / 128), 256, 0, stream>>>(hb, w2t, pair_tok2, pair_w, mt_e, mt_r0, nmt, ob);
    combine_kernel<<<TOK, 256, 0, stream>>>(ob, out);
}

// Round 12
// 1326.579 us; speedup vs baseline: 1.0420x; 1.0420x over previous
//
#include <hip/hip_runtime.h>
#include <hip/hip_bf16.h>
#include <hip/hip_fp16.h>

// ---- problem constants ----
#define TOK 8192      // 4*2048 tokens
#define HD 2048      // hidden
#define ID 4096      // intermediate
#define NE 8         // experts
#define NPAIR (TOK*2) // token-expert pairs (TOPK=2)
#define BM 128
#define MAXMT (NPAIR/BM + NE)   // 136 worst-case M-tiles
#define PPAD (NPAIR + NE*BM)    // 17408 worst-case padded rows (136*128)
#define G1GRID (MAXMT * (ID / 64))      // 8704 gemm1 blocks
#define P2GRID ((ID / 64) * (HD / 64) * NE)  // 16384 prep_w2 blocks
#define RGRID (TOK / 4)                 // 2048 router blocks
#define P13GRID ((HD / 64) * (ID / 64) * NE * 2)  // 32768 prep_w13 blocks

typedef unsigned short u16;
typedef unsigned int u32;
typedef __attribute__((ext_vector_type(4))) float f32x4;
typedef __attribute__((ext_vector_type(4))) int   i32x4;
typedef u16 u16x4 __attribute__((ext_vector_type(4)));

__device__ __forceinline__ u16 f2h(float f) {
    __half h = __float2half_rn(f);
    return *reinterpret_cast<u16*>(&h);
}

// K-tiled layout for staged fp16 matrices (all but gathered xh):
//   element(r, k) -> (r>>7)*(K_TOTAL*128) + (k>>6)*8192 + (r&127)*64 + (k&63)

// ---------------- fused1: router (+x cast) || prep_w13 ----------------
__global__ __launch_bounds__(256) void fused1_kernel(
    const float* __restrict__ x, const float* __restrict__ wg,
    u16* __restrict__ xh, int* __restrict__ top_e, float* __restrict__ top_w,
    int* __restrict__ counts,
    const float* __restrict__ w1, const float* __restrict__ w3,
    u16* __restrict__ wcat) {
    __shared__ u16 shm[64 * 68];
    const int tid = threadIdx.x;
    if ((int)blockIdx.x < RGRID) {
        // ---- router body ----
        int t = blockIdx.x * 4 + (tid >> 6);
        int l = tid & 63;
        const float* xr = x + (size_t)t * HD;
        u16* xo = xh + (size_t)t * HD;
        float acc[NE];
#pragma unroll
        for (int e = 0; e < NE; ++e) acc[e] = 0.f;
        for (int h0 = 0; h0 < HD; h0 += 64) {
            int h = h0 + l;
            float xv = xr[h];
            xo[h] = f2h(xv);
            const f32x4* wr = (const f32x4*)(wg + (size_t)h * NE);
            f32x4 w0 = wr[0], w1v = wr[1];
#pragma unroll
            for (int i = 0; i < 4; ++i) { acc[i] += xv * w0[i]; acc[4 + i] += xv * w1v[i]; }
        }
#pragma unroll
        for (int e = 0; e < NE; ++e) {
            float v = acc[e];
            for (int s = 32; s >= 1; s >>= 1) v += __shfl_xor(v, s);
            acc[e] = v;
        }
        if (l == 0) {
            float li[NE], mx = -1e30f;
#pragma unroll
            for (int e = 0; e < NE; ++e) { li[e] = 30.f * tanhf(acc[e] * (1.f / 30.f)); mx = fmaxf(mx, li[e]); }
            float p[NE], se = 0.f;
#pragma unroll
            for (int e = 0; e < NE; ++e) { p[e] = expf(li[e] - mx); se += p[e]; }
            float inv = 1.f / se;
            int i1 = 0; float p1 = p[0];
#pragma unroll
            for (int e = 1; e < NE; ++e) if (p[e] > p1) { p1 = p[e]; i1 = e; }
            int i2 = -1; float p2 = -1e30f;
#pragma unroll
            for (int e = 0; e < NE; ++e) if (e != i1 && p[e] > p2) { p2 = p[e]; i2 = e; }
            top_e[t * 2] = i1; top_e[t * 2 + 1] = i2;
            top_w[t * 2] = p1 * inv; top_w[t * 2 + 1] = p2 * inv;
            atomicAdd(&counts[i1], 1); atomicAdd(&counts[i2], 1);
        }
    } else {
        // ---- prep_w13 body: bid -> (kx, ny, z) of dim3(32, 64, 16) ----
        int bid = blockIdx.x - RGRID;
        int kx = bid & 31, ny = (bid >> 5) & 63, z = bid >> 11;
        const int k0 = kx * 64, n0 = ny * 64;
        const int e = z >> 1, which = z & 1;
        const float* src = (which ? w3 : w1) + (size_t)e * HD * ID;
        u16* dst = wcat + (size_t)e * 2 * ID * HD;
        const int r = tid >> 4, c4 = (tid & 15) * 4;
#pragma unroll
        for (int i = 0; i < 4; ++i) {
            int k = k0 + r + 16 * i;
            f32x4 v = *(const f32x4*)(src + (size_t)k * ID + n0 + c4);
#pragma unroll
            for (int j = 0; j < 4; ++j) shm[(c4 + j) * 68 + r + 16 * i] = f2h(v[j]);
        }
        __syncthreads();
#pragma unroll
        for (int i = 0; i < 4; ++i) {
            int nl = r + 16 * i;
            int n = n0 + nl;
            int wr = ((n >> 4) << 5) | (which << 4) | (n & 15);
            u16x4 o;
#pragma unroll
            for (int j = 0; j < 4; ++j) o[j] = shm[nl * 68 + c4 + j];
            size_t off = (size_t)(wr >> 7) * (HD * 128) + (size_t)(k0 >> 6) * 8192
                       + (wr & 127) * 64 + c4;
            *(u16x4*)(dst + off) = o;
        }
    }
}

// ---------------- standalone prep_w2 (planB fallback) ----------------
__global__ __launch_bounds__(256) void prep_w2_kernel(const float* __restrict__ w2,
                                                      u16* __restrict__ w2t) {
    __shared__ u16 tile[64][68];
    const int k0 = blockIdx.x * 64, n0 = blockIdx.y * 64;
    const int e = blockIdx.z;
    const float* src = w2 + (size_t)e * ID * HD;
    u16* dst = w2t + (size_t)e * ID * HD;
    const int tid = threadIdx.x, r = tid >> 4, c4 = (tid & 15) * 4;
#pragma unroll
    for (int i = 0; i < 4; ++i) {
        int k = k0 + r + 16 * i;
        f32x4 v = *(const f32x4*)(src + (size_t)k * HD + n0 + c4);
#pragma unroll
        for (int j = 0; j < 4; ++j) tile[c4 + j][r + 16 * i] = f2h(v[j]);
    }
    __syncthreads();
#pragma unroll
    for (int i = 0; i < 4; ++i) {
        int nl = r + 16 * i;
        int rr = n0 + nl;
        u16x4 o;
#pragma unroll
        for (int j = 0; j < 4; ++j) o[j] = tile[nl][c4 + j];
        size_t off = (size_t)(rr >> 7) * (ID * 128) + (size_t)(k0 >> 6) * 8192
                   + (rr & 127) * 64 + c4;
        *(u16x4*)(dst + off) = o;
    }
}

// ---------------- offsets + M-tile table (1 thread) ----------------
__global__ void offsets_kernel(const int* __restrict__ counts, int* __restrict__ offs,
                               int* __restrict__ mt_e, int* __restrict__ mt_r0,
                               int* __restrict__ nmt) {
    if (threadIdx.x != 0) return;
    int off = 0, n = 0;
    for (int e = 0; e < NE; ++e) {
        offs[e] = off;
        int c = counts[e];
        int nt = (c + BM - 1) >> 7;
        for (int j = 0; j < nt; ++j) { mt_e[n] = e; mt_r0[n] = off + j * BM; ++n; }
        off += nt * BM;
    }
    offs[NE] = off;
    *nmt = n;
}

// ---------------- deterministic per-expert compaction ----------------
__global__ void scatter_kernel(const int* __restrict__ top_e, const float* __restrict__ top_w,
                               const int* __restrict__ counts, const int* __restrict__ offs,
                               int* __restrict__ pair_tok2, float* __restrict__ pair_w) {
    const int e = blockIdx.x;
    const int tid = threadIdx.x;
    __shared__ int sc[256];
    int base = offs[e];
    for (int start = 0; start < TOK; start += 256) {
        int tk = start + tid;
        int m = 0; float w = 0.f; int slot = 0;
        int e0 = top_e[tk * 2], e1 = top_e[tk * 2 + 1];
        if (e0 == e) { m = 1; w = top_w[tk * 2]; slot = 0; }
        else if (e1 == e) { m = 1; w = top_w[tk * 2 + 1]; slot = 1; }
        sc[tid] = m;
        __syncthreads();
        for (int s = 1; s < 256; s <<= 1) {
            int v = (tid >= s) ? sc[tid - s] : 0;
            __syncthreads();
            sc[tid] += v;
            __syncthreads();
        }
        if (m) { int pos = base + sc[tid] - 1; pair_tok2[pos] = tk * 2 + slot; pair_w[pos] = w; }
        base += sc[255];
        __syncthreads();
    }
    int cnt = counts[e];
    int padded = (cnt + BM - 1) & ~(BM - 1);
    for (int r = cnt + tid; r < padded; r += 256) {
        pair_tok2[offs[e] + r] = -2;
        pair_w[offs[e] + r] = 0.f;
    }
}

// ---------------- fused2: gemm1 || prep_w2 (planA) ----------------
// blocks [0, G1GRID): gemm1 (m97 structure, mt-major XCD clusters)
// blocks [G1GRID, G1GRID+P2GRID): prep_w2 into separate w2t buffer
__global__ __launch_bounds__(256, 3) void fused2_kernel(
    const u16* __restrict__ xh, const u16* __restrict__ wcat,
    const int* __restrict__ pair_tok2, const int* __restrict__ mt_e,
    const int* __restrict__ mt_r0, const int* __restrict__ nmt,
    u16* __restrict__ hb,
    const float* __restrict__ w2, u16* __restrict__ w2t) {
    __shared__ u16 shm[128 * 64 * 2];   // 32 KB; gemm1: sA|sB, prep: tile[64][68]
    const int tid = threadIdx.x;
    if ((int)blockIdx.x >= G1GRID) {
        // ---- prep_w2 body: bid -> (kx, ny, e) of dim3(64, 32, 8) ----
        int bid = blockIdx.x - G1GRID;
        int kx = bid & 63, ny = (bid >> 6) & 31, e = bid >> 11;
        const int k0 = kx * 64, n0 = ny * 64;
        const float* src = w2 + (size_t)e * ID * HD;
        u16* dst = w2t + (size_t)e * ID * HD;
        const int r = tid >> 4, c4 = (tid & 15) * 4;
#pragma unroll
        for (int i = 0; i < 4; ++i) {
            int k = k0 + r + 16 * i;
            f32x4 v = *(const f32x4*)(src + (size_t)k * HD + n0 + c4);
#pragma unroll
            for (int j = 0; j < 4; ++j) shm[(c4 + j) * 68 + r + 16 * i] = f2h(v[j]);
        }
        __syncthreads();
#pragma unroll
        for (int i = 0; i < 4; ++i) {
            int nl = r + 16 * i;
            int rr = n0 + nl;
            u16x4 o;
#pragma unroll
            for (int j = 0; j < 4; ++j) o[j] = shm[nl * 68 + c4 + j];
            size_t off = (size_t)(rr >> 7) * (ID * 128) + (size_t)(k0 >> 6) * 8192
                       + (rr & 127) * 64 + c4;
            *(u16x4*)(dst + off) = o;
        }
        return;
    }
    // ---- gemm1 body ----
    int p = blockIdx.x;
    int x = p & 7, j = p >> 3, c = j >> 6, s = j & 63;
    int C = c * 8 + x;                 // [0,136)
    int mt = (C >> 3) * 8 + (s >> 3);  // mt-major cluster order
    int by = (C & 7) * 8 + (s & 7);
    if (mt >= *nmt) return;
    const int e = mt_e[mt], row0 = mt_r0[mt];
    const int lane = tid & 63, wv = tid >> 6;
    const int wm = wv >> 1, wn = wv & 1;
    u16* sA = shm;
    u16* sB = shm + 128 * 64;

    const u16* asrc[4];
    const u16* bsrc[4];
#pragma unroll
    for (int i = 0; i < 4; ++i) {
        int rl = i * 32 + (tid >> 3);
        int kbs = ((tid & 7) * 16) ^ ((rl & 7) << 4);      // byte offset, pre-swizzled
        int pt2 = pair_tok2[row0 + rl];
        int tok = pt2 < 0 ? 0 : (pt2 >> 1);
        asrc[i] = xh + (size_t)tok * HD + (kbs >> 1);
        bsrc[i] = wcat + (size_t)e * 2 * ID * HD + (size_t)by * (HD * 128)
                + rl * 64 + (kbs >> 1);
    }

    f32x4 acc[4][4];
#pragma unroll
    for (int a = 0; a < 4; ++a)
#pragma unroll
        for (int b = 0; b < 4; ++b) acc[a][b] = (f32x4)0.f;

    for (int kt = 0; kt < HD / 64; ++kt) {
#pragma unroll
        for (int i = 0; i < 4; ++i) {
            __builtin_amdgcn_global_load_lds(
                (const __attribute__((address_space(1))) void*)asrc[i],
                (__attribute__((address_space(3))) void*)(sA + i * 2048 + wv * 512), 16, 0, 0);
            asrc[i] += 64;
        }
#pragma unroll
        for (int i = 0; i < 4; ++i) {
            __builtin_amdgcn_global_load_lds(
                (const __attribute__((address_space(1))) void*)bsrc[i],
                (__attribute__((address_space(3))) void*)(sB + i * 2048 + wv * 512), 16, 0, 0);
            bsrc[i] += 8192;
        }
        __syncthreads();
#pragma unroll
        for (int ks = 0; ks < 2; ++ks) {
            i32x4 a[4], b[4];
#pragma unroll
            for (int mf = 0; mf < 4; ++mf) {
                int rr = wm * 64 + mf * 16 + (lane & 15);
                int lb = ((lane >> 4) * 16 + ks * 64) ^ ((rr & 7) << 4);
                a[mf] = *(const i32x4*)((const char*)sA + rr * 128 + lb);
            }
#pragma unroll
            for (int nf = 0; nf < 4; ++nf) {
                int nn = wn * 64 + nf * 16 + (lane & 15);
                int lb = ((lane >> 4) * 16 + ks * 64) ^ ((nn & 7) << 4);
                b[nf] = *(const i32x4*)((const char*)sB + nn * 128 + lb);
            }
#pragma unroll
            for (int nf = 0; nf < 4; ++nf)
#pragma unroll
                for (int mf = 0; mf < 4; ++mf)
                    asm("v_mfma_f32_16x16x32_f16 %0, %1, %2, %0" : "+v"(acc[mf][nf]) : "v"(a[mf]), "v"(b[nf]));
        }
        __syncthreads();
    }

    // epilogue -> K-tiled hb
#pragma unroll
    for (int mf = 0; mf < 4; ++mf) {
#pragma unroll
        for (int j2 = 0; j2 < 4; ++j2) {
            int rr = row0 + wm * 64 + mf * 16 + (lane >> 4) * 4 + j2;
            u16* hp_ = hb + (size_t)(rr >> 7) * (ID * 128) + (size_t)by * 8192
                     + (rr & 127) * 64 + wn * 32 + (lane & 15);
#pragma unroll
            for (int np = 0; np < 2; ++np) {
                float g = acc[mf][2 * np][j2], u = acc[mf][2 * np + 1][j2];
                float sgl = g / (1.f + expf(-g));
                hp_[np * 16] = f2h(sgl * u);
            }
        }
    }
}

// ---------------- GEMM2: ob[tok*2+slot] = (h@w2t) * weight (plain stores) ----------------
__global__ __launch_bounds__(256, 3) void gemm2_kernel(
    const u16* __restrict__ hb, const u16* __restrict__ w2t,
    const int* __restrict__ pair_tok2, const float* __restrict__ pair_w,
    const int* __restrict__ mt_e, const int* __restrict__ mt_r0, const int* __restrict__ nmt,
    float* __restrict__ ob) {
    int p = blockIdx.x;
    int x = p & 7, j = p >> 3, c = j >> 6, s = j & 63;
    int C = c * 8 + x;                 // [0,40)
    int mt = C * 4 + (s >> 4);         // [0,160), padded
    int by = s & 15;                   // [0,16)
    if (mt >= *nmt) return;
    const int e = mt_e[mt], row0 = mt_r0[mt];
    const int tid = threadIdx.x, lane = tid & 63, wv = tid >> 6;
    const int wm = wv >> 1, wn = wv & 1;

    __shared__ u16 sA[128 * 64];
    __shared__ u16 sB[128 * 64];

    const u16* asrc[4];
    const u16* bsrc[4];
#pragma unroll
    for (int i = 0; i < 4; ++i) {
        int rl = i * 32 + (tid >> 3);
        int kbs = ((tid & 7) * 16) ^ ((rl & 7) << 4);
        asrc[i] = hb + (size_t)(row0 >> 7) * (ID * 128) + rl * 64 + (kbs >> 1);
        bsrc[i] = w2t + (size_t)e * HD * ID + (size_t)by * (ID * 128) + rl * 64 + (kbs >> 1);
    }

    f32x4 acc[4][4];
#pragma unroll
    for (int a = 0; a < 4; ++a)
#pragma unroll
        for (int b = 0; b < 4; ++b) acc[a][b] = (f32x4)0.f;

    for (int kt = 0; kt < ID / 64; ++kt) {
#pragma unroll
        for (int i = 0; i < 4; ++i) {
            __builtin_amdgcn_global_load_lds(
                (const __attribute__((address_space(1))) void*)asrc[i],
                (__attribute__((address_space(3))) void*)(sA + i * 2048 + wv * 512), 16, 0, 0);
            asrc[i] += 8192;
        }
#pragma unroll
        for (int i = 0; i < 4; ++i) {
            __builtin_amdgcn_global_load_lds(
                (const __attribute__((address_space(1))) void*)bsrc[i],
                (__attribute__((address_space(3))) void*)(sB + i * 2048 + wv * 512), 16, 0, 0);
            bsrc[i] += 8192;
        }
        __syncthreads();
#pragma unroll
        for (int ks = 0; ks < 2; ++ks) {
            i32x4 a[4], b[4];
#pragma unroll
            for (int mf = 0; mf < 4; ++mf) {
                int rr = wm * 64 + mf * 16 + (lane & 15);
                int lb = ((lane >> 4) * 16 + ks * 64) ^ ((rr & 7) << 4);
                a[mf] = *(const i32x4*)((const char*)sA + rr * 128 + lb);
            }
#pragma unroll
            for (int nf = 0; nf < 4; ++nf) {
                int nn = wn * 64 + nf * 16 + (lane & 15);
                int lb = ((lane >> 4) * 16 + ks * 64) ^ ((nn & 7) << 4);
                b[nf] = *(const i32x4*)((const char*)sB + nn * 128 + lb);
            }
#pragma unroll
            for (int nf = 0; nf < 4; ++nf)
#pragma unroll
                for (int mf = 0; mf < 4; ++mf)
                    asm("v_mfma_f32_16x16x32_f16 %0, %1, %2, %0" : "+v"(acc[mf][nf]) : "v"(a[mf]), "v"(b[nf]));
        }
        __syncthreads();
    }

#pragma unroll
    for (int mf = 0; mf < 4; ++mf) {
#pragma unroll
        for (int j2 = 0; j2 < 4; ++j2) {
            int rr = row0 + wm * 64 + mf * 16 + (lane >> 4) * 4 + j2;
            int pt2 = pair_tok2[rr];
            float wt = pair_w[rr];
            if (pt2 >= 0) {
                float* op = ob + (size_t)pt2 * HD + by * 128 + wn * 64 + (lane & 15);
#pragma unroll
                for (int nf = 0; nf < 4; ++nf) {
                    op[nf * 16] = acc[mf][nf][j2] * wt;
                }
            }
        }
    }
}

// ---------------- combine: out[t] = ob[2t] + ob[2t+1] ----------------
__global__ __launch_bounds__(256) void combine_kernel(const float* __restrict__ ob,
                                                      float* __restrict__ out) {
    int t = blockIdx.x;
    const f32x4* r0 = (const f32x4*)(ob + (size_t)(2 * t) * HD);
    const f32x4* r1 = (const f32x4*)(ob + (size_t)(2 * t + 1) * HD);
    f32x4* o = (f32x4*)(out + (size_t)t * HD);
#pragma unroll
    for (int i = 0; i < 2; ++i) {
        int idx = threadIdx.x + i * 256;
        o[idx] = r0[idx] + r1[idx];
    }
}

extern "C" void kernel_launch(void* const* d_in, const int* in_sizes, int n_in,
                              void* d_out, int out_size, void* d_ws, size_t ws_size,
                              hipStream_t stream) {
    (void)in_sizes; (void)n_in; (void)out_size;
    const float* x  = (const float*)d_in[0];
    const float* wg = (const float*)d_in[1];
    const float* w1 = (const float*)d_in[2];
    const float* w3 = (const float*)d_in[3];
    const float* w2 = (const float*)d_in[4];
    float* out = (float*)d_out;

    char* ws = (char*)d_ws;
    size_t off = 0;
    auto alloc = [&](size_t bytes) -> void* {
        void* p = ws + off;
        off = (off + bytes + 255) & ~(size_t)255;
        return p;
    };
    u16* xh          = (u16*)alloc((size_t)TOK * HD * 2);
    u16* hb          = (u16*)alloc((size_t)PPAD * ID * 2);
    u16* wcat        = (u16*)alloc((size_t)NE * 2 * ID * HD * 2);  // w13 fp16
    float* ob        = (float*)wcat;   // aliases wcat 1st half (dead after gemm1)
    int* pair_tok2   = (int*)alloc((size_t)PPAD * 4);
    float* pair_w    = (float*)alloc((size_t)PPAD * 4);
    int* top_e       = (int*)alloc((size_t)TOK * 2 * 4);
    float* top_w     = (float*)alloc((size_t)TOK * 2 * 4);
    int* counts      = (int*)alloc(64);
    int* offs        = (int*)alloc(64);
    int* mt_e        = (int*)alloc((size_t)MAXMT * 4);
    int* mt_r0       = (int*)alloc((size_t)MAXMT * 4);
    int* nmt         = (int*)alloc(64);

    // planA: separate w2t -> prep_w2 fuses with gemm1 (runs concurrently).
    // planB (small ws): w2t aliases wcat 2nd half, prep_w2 runs after gemm1.
    size_t w2t_bytes = (size_t)NE * ID * HD * 2;
    bool planA = (off + w2t_bytes) <= ws_size;
    u16* w2t = planA ? (u16*)alloc(w2t_bytes)
                     : wcat + (size_t)NE * ID * HD;

    hipMemsetAsync(counts, 0, 64, stream);

    // router || prep_w13 (independent)
    fused1_kernel<<<RGRID + P13GRID, 256, 0, stream>>>(
        x, wg, xh, top_e, top_w, counts, w1, w3, wcat);
    offsets_kernel<<<1, 64, 0, stream>>>(counts, offs, mt_e, mt_r0, nmt);
    scatter_kernel<<<NE, 256, 0, stream>>>(top_e, top_w, counts, offs, pair_tok2, pair_w);
    if (planA) {
        // gemm1 || prep_w2 (independent buffers)
        fused2_kernel<<<G1GRID + P2GRID, 256, 0, stream>>>(
            xh, wcat, pair_tok2, mt_e, mt_r0, nmt, hb, w2, w2t);
    } else {
        fused2_kernel<<<G1GRID, 256, 0, stream>>>(
            xh, wcat, pair_tok2, mt_e, mt_r0, nmt, hb, w2, w2t);
        prep_w2_kernel<<<dim3(ID / 64, HD / 64, NE), 256, 0, stream>>>(w2, w2t);
    }
    // gemm2: mt padded to 160 x 16 by, XCD-clustered (4mt x 16by clusters)
    gemm2_kernel<<<160 * (HD / 128), 256, 0, stream>>>(hb, w2t, pair_tok2, pair_w, mt_e, mt_r0, nmt, ob);
    combine_kernel<<<TOK, 256, 0, stream>>>(ob, out);
}

// Round 13
// 1294.112 us; speedup vs baseline: 1.0682x; 1.0251x over previous
//
#include <hip/hip_runtime.h>
#include <hip/hip_bf16.h>
#include <hip/hip_fp16.h>

// ---- problem constants ----
#define TOK 8192      // 4*2048 tokens
#define HD 2048      // hidden
#define ID 4096      // intermediate
#define NE 8         // experts
#define NPAIR (TOK*2) // token-expert pairs (TOPK=2)
#define BM 128
#define MAXMT (NPAIR/BM + NE)   // 136 worst-case M-tiles
#define PPAD (NPAIR + NE*BM)    // 17408 worst-case padded rows (136*128)
#define G1GRID (MAXMT * (ID / 64))      // 8704 gemm1 blocks
#define P2GRID ((ID / 64) * (HD / 64) * NE)  // 16384 prep_w2 blocks
#define RGRID (TOK / 4)                 // 2048 router blocks
#define P13GRID ((HD / 64) * (ID / 64) * NE * 2)  // 32768 prep_w13 blocks

typedef unsigned short u16;
typedef unsigned int u32;
typedef __attribute__((ext_vector_type(4))) float f32x4;
typedef __attribute__((ext_vector_type(4))) int   i32x4;
typedef u16 u16x4 __attribute__((ext_vector_type(4)));
typedef u16 u16x8 __attribute__((ext_vector_type(8)));

__device__ __forceinline__ u16 f2h(float f) {
    __half h = __float2half_rn(f);
    return *reinterpret_cast<u16*>(&h);
}
__device__ __forceinline__ float h2f(u16 u) {
    __half h = *reinterpret_cast<__half*>(&u);
    return __half2float(h);
}

// K-tiled layout for staged fp16 matrices (all but gathered xh):
//   element(r, k) -> (r>>7)*(K_TOTAL*128) + (k>>6)*8192 + (r&127)*64 + (k&63)

// ---------------- fused1: router (+x cast) || prep_w13 ----------------
__global__ __launch_bounds__(256) void fused1_kernel(
    const float* __restrict__ x, const float* __restrict__ wg,
    u16* __restrict__ xh, int* __restrict__ top_e, float* __restrict__ top_w,
    int* __restrict__ counts,
    const float* __restrict__ w1, const float* __restrict__ w3,
    u16* __restrict__ wcat) {
    __shared__ u16 shm[64 * 68];
    const int tid = threadIdx.x;
    if ((int)blockIdx.x < RGRID) {
        // ---- router body ----
        int t = blockIdx.x * 4 + (tid >> 6);
        int l = tid & 63;
        const float* xr = x + (size_t)t * HD;
        u16* xo = xh + (size_t)t * HD;
        float acc[NE];
#pragma unroll
        for (int e = 0; e < NE; ++e) acc[e] = 0.f;
        for (int h0 = 0; h0 < HD; h0 += 64) {
            int h = h0 + l;
            float xv = xr[h];
            xo[h] = f2h(xv);
            const f32x4* wr = (const f32x4*)(wg + (size_t)h * NE);
            f32x4 w0 = wr[0], w1v = wr[1];
#pragma unroll
            for (int i = 0; i < 4; ++i) { acc[i] += xv * w0[i]; acc[4 + i] += xv * w1v[i]; }
        }
#pragma unroll
        for (int e = 0; e < NE; ++e) {
            float v = acc[e];
            for (int s = 32; s >= 1; s >>= 1) v += __shfl_xor(v, s);
            acc[e] = v;
        }
        if (l == 0) {
            float li[NE], mx = -1e30f;
#pragma unroll
            for (int e = 0; e < NE; ++e) { li[e] = 30.f * tanhf(acc[e] * (1.f / 30.f)); mx = fmaxf(mx, li[e]); }
            float p[NE], se = 0.f;
#pragma unroll
            for (int e = 0; e < NE; ++e) { p[e] = expf(li[e] - mx); se += p[e]; }
            float inv = 1.f / se;
            int i1 = 0; float p1 = p[0];
#pragma unroll
            for (int e = 1; e < NE; ++e) if (p[e] > p1) { p1 = p[e]; i1 = e; }
            int i2 = -1; float p2 = -1e30f;
#pragma unroll
            for (int e = 0; e < NE; ++e) if (e != i1 && p[e] > p2) { p2 = p[e]; i2 = e; }
            top_e[t * 2] = i1; top_e[t * 2 + 1] = i2;
            top_w[t * 2] = p1 * inv; top_w[t * 2 + 1] = p2 * inv;
            atomicAdd(&counts[i1], 1); atomicAdd(&counts[i2], 1);
        }
    } else {
        // ---- prep_w13 body: bid -> (kx, ny, z) of dim3(32, 64, 16) ----
        int bid = blockIdx.x - RGRID;
        int kx = bid & 31, ny = (bid >> 5) & 63, z = bid >> 11;
        const int k0 = kx * 64, n0 = ny * 64;
        const int e = z >> 1, which = z & 1;
        const float* src = (which ? w3 : w1) + (size_t)e * HD * ID;
        u16* dst = wcat + (size_t)e * 2 * ID * HD;
        const int r = tid >> 4, c4 = (tid & 15) * 4;
#pragma unroll
        for (int i = 0; i < 4; ++i) {
            int k = k0 + r + 16 * i;
            f32x4 v = *(const f32x4*)(src + (size_t)k * ID + n0 + c4);
#pragma unroll
            for (int j = 0; j < 4; ++j) shm[(c4 + j) * 68 + r + 16 * i] = f2h(v[j]);
        }
        __syncthreads();
#pragma unroll
        for (int i = 0; i < 4; ++i) {
            int nl = r + 16 * i;
            int n = n0 + nl;
            int wr = ((n >> 4) << 5) | (which << 4) | (n & 15);
            u16x4 o;
#pragma unroll
            for (int j = 0; j < 4; ++j) o[j] = shm[nl * 68 + c4 + j];
            size_t off = (size_t)(wr >> 7) * (HD * 128) + (size_t)(k0 >> 6) * 8192
                       + (wr & 127) * 64 + c4;
            *(u16x4*)(dst + off) = o;
        }
    }
}

// ---------------- standalone prep_w2 (planB fallback) ----------------
__global__ __launch_bounds__(256) void prep_w2_kernel(const float* __restrict__ w2,
                                                      u16* __restrict__ w2t) {
    __shared__ u16 tile[64][68];
    const int k0 = blockIdx.x * 64, n0 = blockIdx.y * 64;
    const int e = blockIdx.z;
    const float* src = w2 + (size_t)e * ID * HD;
    u16* dst = w2t + (size_t)e * ID * HD;
    const int tid = threadIdx.x, r = tid >> 4, c4 = (tid & 15) * 4;
#pragma unroll
    for (int i = 0; i < 4; ++i) {
        int k = k0 + r + 16 * i;
        f32x4 v = *(const f32x4*)(src + (size_t)k * HD + n0 + c4);
#pragma unroll
        for (int j = 0; j < 4; ++j) tile[c4 + j][r + 16 * i] = f2h(v[j]);
    }
    __syncthreads();
#pragma unroll
    for (int i = 0; i < 4; ++i) {
        int nl = r + 16 * i;
        int rr = n0 + nl;
        u16x4 o;
#pragma unroll
        for (int j = 0; j < 4; ++j) o[j] = tile[nl][c4 + j];
        size_t off = (size_t)(rr >> 7) * (ID * 128) + (size_t)(k0 >> 6) * 8192
                   + (rr & 127) * 64 + c4;
        *(u16x4*)(dst + off) = o;
    }
}

// ---------------- offsets + M-tile table (1 thread) ----------------
__global__ void offsets_kernel(const int* __restrict__ counts, int* __restrict__ offs,
                               int* __restrict__ mt_e, int* __restrict__ mt_r0,
                               int* __restrict__ nmt) {
    if (threadIdx.x != 0) return;
    int off = 0, n = 0;
    for (int e = 0; e < NE; ++e) {
        offs[e] = off;
        int c = counts[e];
        int nt = (c + BM - 1) >> 7;
        for (int j = 0; j < nt; ++j) { mt_e[n] = e; mt_r0[n] = off + j * BM; ++n; }
        off += nt * BM;
    }
    offs[NE] = off;
    *nmt = n;
}

// ---------------- deterministic per-expert compaction ----------------
__global__ void scatter_kernel(const int* __restrict__ top_e, const float* __restrict__ top_w,
                               const int* __restrict__ counts, const int* __restrict__ offs,
                               int* __restrict__ pair_tok2, float* __restrict__ pair_w) {
    const int e = blockIdx.x;
    const int tid = threadIdx.x;
    __shared__ int sc[256];
    int base = offs[e];
    for (int start = 0; start < TOK; start += 256) {
        int tk = start + tid;
        int m = 0; float w = 0.f; int slot = 0;
        int e0 = top_e[tk * 2], e1 = top_e[tk * 2 + 1];
        if (e0 == e) { m = 1; w = top_w[tk * 2]; slot = 0; }
        else if (e1 == e) { m = 1; w = top_w[tk * 2 + 1]; slot = 1; }
        sc[tid] = m;
        __syncthreads();
        for (int s = 1; s < 256; s <<= 1) {
            int v = (tid >= s) ? sc[tid - s] : 0;
            __syncthreads();
            sc[tid] += v;
            __syncthreads();
        }
        if (m) { int pos = base + sc[tid] - 1; pair_tok2[pos] = tk * 2 + slot; pair_w[pos] = w; }
        base += sc[255];
        __syncthreads();
    }
    int cnt = counts[e];
    int padded = (cnt + BM - 1) & ~(BM - 1);
    for (int r = cnt + tid; r < padded; r += 256) {
        pair_tok2[offs[e] + r] = -2;
        pair_w[offs[e] + r] = 0.f;
    }
}

// ---------------- fused2: gemm1 || prep_w2 (planA) ----------------
__global__ __launch_bounds__(256, 3) void fused2_kernel(
    const u16* __restrict__ xh, const u16* __restrict__ wcat,
    const int* __restrict__ pair_tok2, const int* __restrict__ mt_e,
    const int* __restrict__ mt_r0, const int* __restrict__ nmt,
    u16* __restrict__ hb,
    const float* __restrict__ w2, u16* __restrict__ w2t) {
    __shared__ u16 shm[128 * 64 * 2];   // 32 KB; gemm1: sA|sB, prep: tile[64][68]
    const int tid = threadIdx.x;
    if ((int)blockIdx.x >= G1GRID) {
        // ---- prep_w2 body: bid -> (kx, ny, e) of dim3(64, 32, 8) ----
        int bid = blockIdx.x - G1GRID;
        int kx = bid & 63, ny = (bid >> 6) & 31, e = bid >> 11;
        const int k0 = kx * 64, n0 = ny * 64;
        const float* src = w2 + (size_t)e * ID * HD;
        u16* dst = w2t + (size_t)e * ID * HD;
        const int r = tid >> 4, c4 = (tid & 15) * 4;
#pragma unroll
        for (int i = 0; i < 4; ++i) {
            int k = k0 + r + 16 * i;
            f32x4 v = *(const f32x4*)(src + (size_t)k * HD + n0 + c4);
#pragma unroll
            for (int j = 0; j < 4; ++j) shm[(c4 + j) * 68 + r + 16 * i] = f2h(v[j]);
        }
        __syncthreads();
#pragma unroll
        for (int i = 0; i < 4; ++i) {
            int nl = r + 16 * i;
            int rr = n0 + nl;
            u16x4 o;
#pragma unroll
            for (int j = 0; j < 4; ++j) o[j] = shm[nl * 68 + c4 + j];
            size_t off = (size_t)(rr >> 7) * (ID * 128) + (size_t)(k0 >> 6) * 8192
                       + (rr & 127) * 64 + c4;
            *(u16x4*)(dst + off) = o;
        }
        return;
    }
    // ---- gemm1 body ----
    int p = blockIdx.x;
    int x = p & 7, j = p >> 3, c = j >> 6, s = j & 63;
    int C = c * 8 + x;                 // [0,136)
    int mt = (C >> 3) * 8 + (s >> 3);  // mt-major cluster order
    int by = (C & 7) * 8 + (s & 7);
    if (mt >= *nmt) return;
    const int e = mt_e[mt], row0 = mt_r0[mt];
    const int lane = tid & 63, wv = tid >> 6;
    const int wm = wv >> 1, wn = wv & 1;
    u16* sA = shm;
    u16* sB = shm + 128 * 64;

    const u16* asrc[4];
    const u16* bsrc[4];
#pragma unroll
    for (int i = 0; i < 4; ++i) {
        int rl = i * 32 + (tid >> 3);
        int kbs = ((tid & 7) * 16) ^ ((rl & 7) << 4);      // byte offset, pre-swizzled
        int pt2 = pair_tok2[row0 + rl];
        int tok = pt2 < 0 ? 0 : (pt2 >> 1);
        asrc[i] = xh + (size_t)tok * HD + (kbs >> 1);
        bsrc[i] = wcat + (size_t)e * 2 * ID * HD + (size_t)by * (HD * 128)
                + rl * 64 + (kbs >> 1);
    }

    f32x4 acc[4][4];
#pragma unroll
    for (int a = 0; a < 4; ++a)
#pragma unroll
        for (int b = 0; b < 4; ++b) acc[a][b] = (f32x4)0.f;

    for (int kt = 0; kt < HD / 64; ++kt) {
#pragma unroll
        for (int i = 0; i < 4; ++i) {
            __builtin_amdgcn_global_load_lds(
                (const __attribute__((address_space(1))) void*)asrc[i],
                (__attribute__((address_space(3))) void*)(sA + i * 2048 + wv * 512), 16, 0, 0);
            asrc[i] += 64;
        }
#pragma unroll
        for (int i = 0; i < 4; ++i) {
            __builtin_amdgcn_global_load_lds(
                (const __attribute__((address_space(1))) void*)bsrc[i],
                (__attribute__((address_space(3))) void*)(sB + i * 2048 + wv * 512), 16, 0, 0);
            bsrc[i] += 8192;
        }
        __syncthreads();
#pragma unroll
        for (int ks = 0; ks < 2; ++ks) {
            i32x4 a[4], b[4];
#pragma unroll
            for (int mf = 0; mf < 4; ++mf) {
                int rr = wm * 64 + mf * 16 + (lane & 15);
                int lb = ((lane >> 4) * 16 + ks * 64) ^ ((rr & 7) << 4);
                a[mf] = *(const i32x4*)((const char*)sA + rr * 128 + lb);
            }
#pragma unroll
            for (int nf = 0; nf < 4; ++nf) {
                int nn = wn * 64 + nf * 16 + (lane & 15);
                int lb = ((lane >> 4) * 16 + ks * 64) ^ ((nn & 7) << 4);
                b[nf] = *(const i32x4*)((const char*)sB + nn * 128 + lb);
            }
#pragma unroll
            for (int nf = 0; nf < 4; ++nf)
#pragma unroll
                for (int mf = 0; mf < 4; ++mf)
                    asm("v_mfma_f32_16x16x32_f16 %0, %1, %2, %0" : "+v"(acc[mf][nf]) : "v"(a[mf]), "v"(b[nf]));
        }
        __syncthreads();
    }

    // epilogue -> K-tiled hb
#pragma unroll
    for (int mf = 0; mf < 4; ++mf) {
#pragma unroll
        for (int j2 = 0; j2 < 4; ++j2) {
            int rr = row0 + wm * 64 + mf * 16 + (lane >> 4) * 4 + j2;
            u16* hp_ = hb + (size_t)(rr >> 7) * (ID * 128) + (size_t)by * 8192
                     + (rr & 127) * 64 + wn * 32 + (lane & 15);
#pragma unroll
            for (int np = 0; np < 2; ++np) {
                float g = acc[mf][2 * np][j2], u = acc[mf][2 * np + 1][j2];
                float sgl = g / (1.f + expf(-g));
                hp_[np * 16] = f2h(sgl * u);
            }
        }
    }
}

// ---------------- GEMM2: ob16[tok*2+slot] = fp16((h@w2t) * weight) ----------------
// Cluster = 8mt x 8by (64 blocks, fits XCD residency), mt-major order:
// w2t by-panel refetch drops 4.3x -> 2.2x per expert; hb's 2nd by-group
// re-read hits L3-warm lines (mt-major adjacency).
__global__ __launch_bounds__(256, 3) void gemm2_kernel(
    const u16* __restrict__ hb, const u16* __restrict__ w2t,
    const int* __restrict__ pair_tok2, const float* __restrict__ pair_w,
    const int* __restrict__ mt_e, const int* __restrict__ mt_r0, const int* __restrict__ nmt,
    u16* __restrict__ ob) {
    int p = blockIdx.x;                // [0, 2560)
    int x = p & 7, j = p >> 3;         // XCD, seq within XCD [0,320)
    int c = j >> 6, s = j & 63;        // 64-block cluster, slot
    int C = c * 8 + x;                 // [0,40)
    int mtg = C >> 1, byg = C & 1;     // mt-major: consecutive C share mtg
    int mt = mtg * 8 + (s >> 3);       // [0,160), padded
    int by = byg * 8 + (s & 7);        // [0,16)
    if (mt >= *nmt) return;
    const int e = mt_e[mt], row0 = mt_r0[mt];
    const int tid = threadIdx.x, lane = tid & 63, wv = tid >> 6;
    const int wm = wv >> 1, wn = wv & 1;

    __shared__ u16 sA[128 * 64];
    __shared__ u16 sB[128 * 64];

    const u16* asrc[4];
    const u16* bsrc[4];
#pragma unroll
    for (int i = 0; i < 4; ++i) {
        int rl = i * 32 + (tid >> 3);
        int kbs = ((tid & 7) * 16) ^ ((rl & 7) << 4);
        asrc[i] = hb + (size_t)(row0 >> 7) * (ID * 128) + rl * 64 + (kbs >> 1);
        bsrc[i] = w2t + (size_t)e * HD * ID + (size_t)by * (ID * 128) + rl * 64 + (kbs >> 1);
    }

    f32x4 acc[4][4];
#pragma unroll
    for (int a = 0; a < 4; ++a)
#pragma unroll
        for (int b = 0; b < 4; ++b) acc[a][b] = (f32x4)0.f;

    for (int kt = 0; kt < ID / 64; ++kt) {
#pragma unroll
        for (int i = 0; i < 4; ++i) {
            __builtin_amdgcn_global_load_lds(
                (const __attribute__((address_space(1))) void*)asrc[i],
                (__attribute__((address_space(3))) void*)(sA + i * 2048 + wv * 512), 16, 0, 0);
            asrc[i] += 8192;
        }
#pragma unroll
        for (int i = 0; i < 4; ++i) {
            __builtin_amdgcn_global_load_lds(
                (const __attribute__((address_space(1))) void*)bsrc[i],
                (__attribute__((address_space(3))) void*)(sB + i * 2048 + wv * 512), 16, 0, 0);
            bsrc[i] += 8192;
        }
        __syncthreads();
#pragma unroll
        for (int ks = 0; ks < 2; ++ks) {
            i32x4 a[4], b[4];
#pragma unroll
            for (int mf = 0; mf < 4; ++mf) {
                int rr = wm * 64 + mf * 16 + (lane & 15);
                int lb = ((lane >> 4) * 16 + ks * 64) ^ ((rr & 7) << 4);
                a[mf] = *(const i32x4*)((const char*)sA + rr * 128 + lb);
            }
#pragma unroll
            for (int nf = 0; nf < 4; ++nf) {
                int nn = wn * 64 + nf * 16 + (lane & 15);
                int lb = ((lane >> 4) * 16 + ks * 64) ^ ((nn & 7) << 4);
                b[nf] = *(const i32x4*)((const char*)sB + nn * 128 + lb);
            }
#pragma unroll
            for (int nf = 0; nf < 4; ++nf)
#pragma unroll
                for (int mf = 0; mf < 4; ++mf)
                    asm("v_mfma_f32_16x16x32_f16 %0, %1, %2, %0" : "+v"(acc[mf][nf]) : "v"(a[mf]), "v"(b[nf]));
        }
        __syncthreads();
    }

#pragma unroll
    for (int mf = 0; mf < 4; ++mf) {
#pragma unroll
        for (int j2 = 0; j2 < 4; ++j2) {
            int rr = row0 + wm * 64 + mf * 16 + (lane >> 4) * 4 + j2;
            int pt2 = pair_tok2[rr];
            float wt = pair_w[rr];
            if (pt2 >= 0) {
                u16* op = ob + (size_t)pt2 * HD + by * 128 + wn * 64 + (lane & 15);
#pragma unroll
                for (int nf = 0; nf < 4; ++nf) {
                    op[nf * 16] = f2h(acc[mf][nf][j2] * wt);
                }
            }
        }
    }
}

// ---------------- combine: out[t] = ob16[2t] + ob16[2t+1] ----------------
__global__ __launch_bounds__(256) void combine_kernel(const u16* __restrict__ ob,
                                                      float* __restrict__ out) {
    int t = blockIdx.x;
    const u16x8* r0 = (const u16x8*)(ob + (size_t)(2 * t) * HD);
    const u16x8* r1 = (const u16x8*)(ob + (size_t)(2 * t + 1) * HD);
    float* o = out + (size_t)t * HD;
    int i = threadIdx.x;      // 256 threads x 8 elems = 2048
    u16x8 a = r0[i], b = r1[i];
    f32x4 o0, o1;
#pragma unroll
    for (int k = 0; k < 4; ++k) {
        o0[k] = h2f(a[k]) + h2f(b[k]);
        o1[k] = h2f(a[4 + k]) + h2f(b[4 + k]);
    }
    ((f32x4*)(o + i * 8))[0] = o0;
    ((f32x4*)(o + i * 8))[1] = o1;
}

extern "C" void kernel_launch(void* const* d_in, const int* in_sizes, int n_in,
                              void* d_out, int out_size, void* d_ws, size_t ws_size,
                              hipStream_t stream) {
    (void)in_sizes; (void)n_in; (void)out_size;
    const float* x  = (const float*)d_in[0];
    const float* wg = (const float*)d_in[1];
    const float* w1 = (const float*)d_in[2];
    const float* w3 = (const float*)d_in[3];
    const float* w2 = (const float*)d_in[4];
    float* out = (float*)d_out;

    char* ws = (char*)d_ws;
    size_t off = 0;
    auto alloc = [&](size_t bytes) -> void* {
        void* p = ws + off;
        off = (off + bytes + 255) & ~(size_t)255;
        return p;
    };
    u16* xh          = (u16*)alloc((size_t)TOK * HD * 2);
    u16* hb          = (u16*)alloc((size_t)PPAD * ID * 2);
    u16* wcat        = (u16*)alloc((size_t)NE * 2 * ID * HD * 2);  // w13 fp16
    u16* ob          = wcat;   // fp16 ob [2*TOK][HD] aliases wcat (dead after gemm1)
    int* pair_tok2   = (int*)alloc((size_t)PPAD * 4);
    float* pair_w    = (float*)alloc((size_t)PPAD * 4);
    int* top_e       = (int*)alloc((size_t)TOK * 2 * 4);
    float* top_w     = (float*)alloc((size_t)TOK * 2 * 4);
    int* counts      = (int*)alloc(64);
    int* offs        = (int*)alloc(64);
    int* mt_e        = (int*)alloc((size_t)MAXMT * 4);
    int* mt_r0       = (int*)alloc((size_t)MAXMT * 4);
    int* nmt         = (int*)alloc(64);

    // planA: separate w2t -> prep_w2 fuses with gemm1 (runs concurrently).
    // planB (small ws): w2t aliases wcat 2nd half, prep_w2 runs after gemm1.
    size_t w2t_bytes = (size_t)NE * ID * HD * 2;
    bool planA = (off + w2t_bytes) <= ws_size;
    u16* w2t = planA ? (u16*)alloc(w2t_bytes)
                     : wcat + (size_t)NE * ID * HD;

    hipMemsetAsync(counts, 0, 64, stream);

    // router || prep_w13 (independent)
    fused1_kernel<<<RGRID + P13GRID, 256, 0, stream>>>(
        x, wg, xh, top_e, top_w, counts, w1, w3, wcat);
    offsets_kernel<<<1, 64, 0, stream>>>(counts, offs, mt_e, mt_r0, nmt);
    scatter_kernel<<<NE, 256, 0, stream>>>(top_e, top_w, counts, offs, pair_tok2, pair_w);
    if (planA) {
        // gemm1 || prep_w2 (independent buffers)
        fused2_kernel<<<G1GRID + P2GRID, 256, 0, stream>>>(
            xh, wcat, pair_tok2, mt_e, mt_r0, nmt, hb, w2, w2t);
    } else {
        fused2_kernel<<<G1GRID, 256, 0, stream>>>(
            xh, wcat, pair_tok2, mt_e, mt_r0, nmt, hb, w2, w2t);
        prep_w2_kernel<<<dim3(ID / 64, HD / 64, NE), 256, 0, stream>>>(w2, w2t);
    }
    // gemm2: mt padded to 160 x 16 by, XCD-clustered (8mt x 8by clusters, 40 clusters)
    gemm2_kernel<<<160 * (HD / 128), 256, 0, stream>>>(hb, w2t, pair_tok2, pair_w, mt_e, mt_r0, nmt, ob);
    combine_kernel<<<TOK, 256, 0, stream>>>(ob, out);
}

// Round 14
// 1268.052 us; speedup vs baseline: 1.0901x; 1.0206x over previous
//
#include <hip/hip_runtime.h>
#include <hip/hip_bf16.h>
#include <hip/hip_fp16.h>

// ---- problem constants ----
#define TOK 8192      // 4*2048 tokens
#define HD 2048      // hidden
#define ID 4096      // intermediate
#define NE 8         // experts
#define NPAIR (TOK*2) // token-expert pairs (TOPK=2)
#define BM 128
#define MAXMT (NPAIR/BM + NE)   // 136 worst-case M-tiles
#define PPAD (NPAIR + NE*BM)    // 17408 worst-case padded rows (136*128)
#define G1GRID (MAXMT * (ID / 64))      // 8704 gemm1 blocks
#define P2GRID ((ID / 64) * (HD / 64) * NE)  // 16384 prep_w2 blocks
#define RGRID (TOK / 4)                 // 2048 router blocks
#define P13GRID ((HD / 64) * (ID / 64) * NE * 2)  // 32768 prep_w13 blocks

typedef unsigned short u16;
typedef unsigned int u32;
typedef __attribute__((ext_vector_type(4))) float f32x4;
typedef __attribute__((ext_vector_type(4))) int   i32x4;
typedef u16 u16x4 __attribute__((ext_vector_type(4)));
typedef u16 u16x8 __attribute__((ext_vector_type(8)));

__device__ __forceinline__ u16 f2h(float f) {
    __half h = __float2half_rn(f);
    return *reinterpret_cast<u16*>(&h);
}
__device__ __forceinline__ float h2f(u16 u) {
    __half h = *reinterpret_cast<__half*>(&u);
    return __half2float(h);
}

// K-tiled layout for staged fp16 matrices (all but gathered xh):
//   element(r, k) -> (r>>7)*(K_TOTAL*128) + (k>>6)*8192 + (r&127)*64 + (k&63)

// ---------------- fused1: router (+x cast) || prep_w13 ----------------
__global__ __launch_bounds__(256) void fused1_kernel(
    const float* __restrict__ x, const float* __restrict__ wg,
    u16* __restrict__ xh, int* __restrict__ top_e, float* __restrict__ top_w,
    int* __restrict__ counts,
    const float* __restrict__ w1, const float* __restrict__ w3,
    u16* __restrict__ wcat) {
    __shared__ u16 shm[64 * 68];
    const int tid = threadIdx.x;
    if ((int)blockIdx.x < RGRID) {
        // ---- router body ----
        int t = blockIdx.x * 4 + (tid >> 6);
        int l = tid & 63;
        const float* xr = x + (size_t)t * HD;
        u16* xo = xh + (size_t)t * HD;
        float acc[NE];
#pragma unroll
        for (int e = 0; e < NE; ++e) acc[e] = 0.f;
        for (int h0 = 0; h0 < HD; h0 += 64) {
            int h = h0 + l;
            float xv = xr[h];
            xo[h] = f2h(xv);
            const f32x4* wr = (const f32x4*)(wg + (size_t)h * NE);
            f32x4 w0 = wr[0], w1v = wr[1];
#pragma unroll
            for (int i = 0; i < 4; ++i) { acc[i] += xv * w0[i]; acc[4 + i] += xv * w1v[i]; }
        }
#pragma unroll
        for (int e = 0; e < NE; ++e) {
            float v = acc[e];
            for (int s = 32; s >= 1; s >>= 1) v += __shfl_xor(v, s);
            acc[e] = v;
        }
        if (l == 0) {
            float li[NE], mx = -1e30f;
#pragma unroll
            for (int e = 0; e < NE; ++e) { li[e] = 30.f * tanhf(acc[e] * (1.f / 30.f)); mx = fmaxf(mx, li[e]); }
            float p[NE], se = 0.f;
#pragma unroll
            for (int e = 0; e < NE; ++e) { p[e] = expf(li[e] - mx); se += p[e]; }
            float inv = 1.f / se;
            int i1 = 0; float p1 = p[0];
#pragma unroll
            for (int e = 1; e < NE; ++e) if (p[e] > p1) { p1 = p[e]; i1 = e; }
            int i2 = -1; float p2 = -1e30f;
#pragma unroll
            for (int e = 0; e < NE; ++e) if (e != i1 && p[e] > p2) { p2 = p[e]; i2 = e; }
            top_e[t * 2] = i1; top_e[t * 2 + 1] = i2;
            top_w[t * 2] = p1 * inv; top_w[t * 2 + 1] = p2 * inv;
            atomicAdd(&counts[i1], 1); atomicAdd(&counts[i2], 1);
        }
    } else {
        // ---- prep_w13 body: bid -> (kx, ny, z) of dim3(32, 64, 16) ----
        int bid = blockIdx.x - RGRID;
        int kx = bid & 31, ny = (bid >> 5) & 63, z = bid >> 11;
        const int k0 = kx * 64, n0 = ny * 64;
        const int e = z >> 1, which = z & 1;
        const float* src = (which ? w3 : w1) + (size_t)e * HD * ID;
        u16* dst = wcat + (size_t)e * 2 * ID * HD;
        const int r = tid >> 4, c4 = (tid & 15) * 4;
#pragma unroll
        for (int i = 0; i < 4; ++i) {
            int k = k0 + r + 16 * i;
            f32x4 v = *(const f32x4*)(src + (size_t)k * ID + n0 + c4);
#pragma unroll
            for (int j = 0; j < 4; ++j) shm[(c4 + j) * 68 + r + 16 * i] = f2h(v[j]);
        }
        __syncthreads();
#pragma unroll
        for (int i = 0; i < 4; ++i) {
            int nl = r + 16 * i;
            int n = n0 + nl;
            int wr = ((n >> 4) << 5) | (which << 4) | (n & 15);
            u16x4 o;
#pragma unroll
            for (int j = 0; j < 4; ++j) o[j] = shm[nl * 68 + c4 + j];
            size_t off = (size_t)(wr >> 7) * (HD * 128) + (size_t)(k0 >> 6) * 8192
                       + (wr & 127) * 64 + c4;
            *(u16x4*)(dst + off) = o;
        }
    }
}

// ---------------- standalone prep_w2 (planB fallback) ----------------
__global__ __launch_bounds__(256) void prep_w2_kernel(const float* __restrict__ w2,
                                                      u16* __restrict__ w2t) {
    __shared__ u16 tile[64][68];
    const int k0 = blockIdx.x * 64, n0 = blockIdx.y * 64;
    const int e = blockIdx.z;
    const float* src = w2 + (size_t)e * ID * HD;
    u16* dst = w2t + (size_t)e * ID * HD;
    const int tid = threadIdx.x, r = tid >> 4, c4 = (tid & 15) * 4;
#pragma unroll
    for (int i = 0; i < 4; ++i) {
        int k = k0 + r + 16 * i;
        f32x4 v = *(const f32x4*)(src + (size_t)k * HD + n0 + c4);
#pragma unroll
        for (int j = 0; j < 4; ++j) tile[c4 + j][r + 16 * i] = f2h(v[j]);
    }
    __syncthreads();
#pragma unroll
    for (int i = 0; i < 4; ++i) {
        int nl = r + 16 * i;
        int rr = n0 + nl;
        u16x4 o;
#pragma unroll
        for (int j = 0; j < 4; ++j) o[j] = tile[nl][c4 + j];
        size_t off = (size_t)(rr >> 7) * (ID * 128) + (size_t)(k0 >> 6) * 8192
                   + (rr & 127) * 64 + c4;
        *(u16x4*)(dst + off) = o;
    }
}

// ---------------- scatter + offsets + mt-tables (merged, ballot scan) ----------------
// Deterministic: ballot order = lane order = token order (identical output to
// the old Hillis-Steele version). Each block recomputes the trivial 8-expert
// prefix from counts; block 0 additionally writes the mt tables.
__global__ void scatter_kernel(const int* __restrict__ top_e, const float* __restrict__ top_w,
                               const int* __restrict__ counts, int* __restrict__ offs,
                               int* __restrict__ mt_e, int* __restrict__ mt_r0,
                               int* __restrict__ nmt,
                               int* __restrict__ pair_tok2, float* __restrict__ pair_w) {
    const int e = blockIdx.x;
    const int tid = threadIdx.x, l = tid & 63, wv = tid >> 6;
    __shared__ int sc[4];
    __shared__ int offs_s[NE + 1];
    if (tid == 0) {
        int off = 0;
        for (int q = 0; q < NE; ++q) {
            offs_s[q] = off;
            off += (counts[q] + BM - 1) & ~(BM - 1);
        }
        offs_s[NE] = off;
    }
    __syncthreads();
    if (e == 0 && tid == 0) {
        int n = 0;
        for (int q = 0; q < NE; ++q) {
            offs[q] = offs_s[q];
            int nt = (counts[q] + BM - 1) >> 7;
            for (int j = 0; j < nt; ++j) { mt_e[n] = q; mt_r0[n] = offs_s[q] + j * BM; ++n; }
        }
        offs[NE] = offs_s[NE];
        *nmt = n;
    }
    int base = offs_s[e];
    for (int start = 0; start < TOK; start += 256) {
        int tk = start + tid;
        int m = 0; float w = 0.f; int slot = 0;
        int e0 = top_e[tk * 2], e1 = top_e[tk * 2 + 1];
        if (e0 == e) { m = 1; w = top_w[tk * 2]; slot = 0; }
        else if (e1 == e) { m = 1; w = top_w[tk * 2 + 1]; slot = 1; }
        unsigned long long b = __ballot(m);
        int wpre = __popcll(b & ((1ull << l) - 1));
        if (l == 0) sc[wv] = __popcll(b);
        __syncthreads();
        int wbase = 0;
#pragma unroll
        for (int q = 0; q < 4; ++q) if (q < wv) wbase += sc[q];
        int total = sc[0] + sc[1] + sc[2] + sc[3];
        if (m) { int pos = base + wbase + wpre; pair_tok2[pos] = tk * 2 + slot; pair_w[pos] = w; }
        base += total;
        __syncthreads();
    }
    int cnt = counts[e];
    int padded = (cnt + BM - 1) & ~(BM - 1);
    for (int r = cnt + tid; r < padded; r += 256) {
        pair_tok2[offs_s[e] + r] = -2;
        pair_w[offs_s[e] + r] = 0.f;
    }
}

// ---------------- fused2: gemm1 || prep_w2 (planA) ----------------
__global__ __launch_bounds__(256, 3) void fused2_kernel(
    const u16* __restrict__ xh, const u16* __restrict__ wcat,
    const int* __restrict__ pair_tok2, const int* __restrict__ mt_e,
    const int* __restrict__ mt_r0, const int* __restrict__ nmt,
    u16* __restrict__ hb,
    const float* __restrict__ w2, u16* __restrict__ w2t) {
    __shared__ u16 shm[128 * 64 * 2];   // 32 KB; gemm1: sA|sB, prep: tile[64][68]
    const int tid = threadIdx.x;
    if ((int)blockIdx.x >= G1GRID) {
        // ---- prep_w2 body: bid -> (kx, ny, e) of dim3(64, 32, 8) ----
        int bid = blockIdx.x - G1GRID;
        int kx = bid & 63, ny = (bid >> 6) & 31, e = bid >> 11;
        const int k0 = kx * 64, n0 = ny * 64;
        const float* src = w2 + (size_t)e * ID * HD;
        u16* dst = w2t + (size_t)e * ID * HD;
        const int r = tid >> 4, c4 = (tid & 15) * 4;
#pragma unroll
        for (int i = 0; i < 4; ++i) {
            int k = k0 + r + 16 * i;
            f32x4 v = *(const f32x4*)(src + (size_t)k * HD + n0 + c4);
#pragma unroll
            for (int j = 0; j < 4; ++j) shm[(c4 + j) * 68 + r + 16 * i] = f2h(v[j]);
        }
        __syncthreads();
#pragma unroll
        for (int i = 0; i < 4; ++i) {
            int nl = r + 16 * i;
            int rr = n0 + nl;
            u16x4 o;
#pragma unroll
            for (int j = 0; j < 4; ++j) o[j] = shm[nl * 68 + c4 + j];
            size_t off = (size_t)(rr >> 7) * (ID * 128) + (size_t)(k0 >> 6) * 8192
                       + (rr & 127) * 64 + c4;
            *(u16x4*)(dst + off) = o;
        }
        return;
    }
    // ---- gemm1 body ----
    int p = blockIdx.x;
    int x = p & 7, j = p >> 3, c = j >> 6, s = j & 63;
    int C = c * 8 + x;                 // [0,136)
    int mt = (C >> 3) * 8 + (s >> 3);  // mt-major cluster order
    int by = (C & 7) * 8 + (s & 7);
    if (mt >= *nmt) return;
    const int e = mt_e[mt], row0 = mt_r0[mt];
    const int lane = tid & 63, wv = tid >> 6;
    const int wm = wv >> 1, wn = wv & 1;
    u16* sA = shm;
    u16* sB = shm + 128 * 64;

    const u16* asrc[4];
    const u16* bsrc[4];
#pragma unroll
    for (int i = 0; i < 4; ++i) {
        int rl = i * 32 + (tid >> 3);
        int kbs = ((tid & 7) * 16) ^ ((rl & 7) << 4);      // byte offset, pre-swizzled
        int pt2 = pair_tok2[row0 + rl];
        int tok = pt2 < 0 ? 0 : (pt2 >> 1);
        asrc[i] = xh + (size_t)tok * HD + (kbs >> 1);
        bsrc[i] = wcat + (size_t)e * 2 * ID * HD + (size_t)by * (HD * 128)
                + rl * 64 + (kbs >> 1);
    }

    f32x4 acc[4][4];
#pragma unroll
    for (int a = 0; a < 4; ++a)
#pragma unroll
        for (int b = 0; b < 4; ++b) acc[a][b] = (f32x4)0.f;

    for (int kt = 0; kt < HD / 64; ++kt) {
#pragma unroll
        for (int i = 0; i < 4; ++i) {
            __builtin_amdgcn_global_load_lds(
                (const __attribute__((address_space(1))) void*)asrc[i],
                (__attribute__((address_space(3))) void*)(sA + i * 2048 + wv * 512), 16, 0, 0);
            asrc[i] += 64;
        }
#pragma unroll
        for (int i = 0; i < 4; ++i) {
            __builtin_amdgcn_global_load_lds(
                (const __attribute__((address_space(1))) void*)bsrc[i],
                (__attribute__((address_space(3))) void*)(sB + i * 2048 + wv * 512), 16, 0, 0);
            bsrc[i] += 8192;
        }
        __syncthreads();
#pragma unroll
        for (int ks = 0; ks < 2; ++ks) {
            i32x4 a[4], b[4];
#pragma unroll
            for (int mf = 0; mf < 4; ++mf) {
                int rr = wm * 64 + mf * 16 + (lane & 15);
                int lb = ((lane >> 4) * 16 + ks * 64) ^ ((rr & 7) << 4);
                a[mf] = *(const i32x4*)((const char*)sA + rr * 128 + lb);
            }
#pragma unroll
            for (int nf = 0; nf < 4; ++nf) {
                int nn = wn * 64 + nf * 16 + (lane & 15);
                int lb = ((lane >> 4) * 16 + ks * 64) ^ ((nn & 7) << 4);
                b[nf] = *(const i32x4*)((const char*)sB + nn * 128 + lb);
            }
#pragma unroll
            for (int nf = 0; nf < 4; ++nf)
#pragma unroll
                for (int mf = 0; mf < 4; ++mf)
                    asm("v_mfma_f32_16x16x32_f16 %0, %1, %2, %0" : "+v"(acc[mf][nf]) : "v"(a[mf]), "v"(b[nf]));
        }
        __syncthreads();
    }

    // epilogue -> K-tiled hb
#pragma unroll
    for (int mf = 0; mf < 4; ++mf) {
#pragma unroll
        for (int j2 = 0; j2 < 4; ++j2) {
            int rr = row0 + wm * 64 + mf * 16 + (lane >> 4) * 4 + j2;
            u16* hp_ = hb + (size_t)(rr >> 7) * (ID * 128) + (size_t)by * 8192
                     + (rr & 127) * 64 + wn * 32 + (lane & 15);
#pragma unroll
            for (int np = 0; np < 2; ++np) {
                float g = acc[mf][2 * np][j2], u = acc[mf][2 * np + 1][j2];
                float sgl = g / (1.f + expf(-g));
                hp_[np * 16] = f2h(sgl * u);
            }
        }
    }
}

// ---------------- GEMM2: ob16[tok*2+slot] = fp16((h@w2t) * weight) ----------------
// Cluster = 8mt x 8by (64 blocks), mt-major order.
__global__ __launch_bounds__(256, 3) void gemm2_kernel(
    const u16* __restrict__ hb, const u16* __restrict__ w2t,
    const int* __restrict__ pair_tok2, const float* __restrict__ pair_w,
    const int* __restrict__ mt_e, const int* __restrict__ mt_r0, const int* __restrict__ nmt,
    u16* __restrict__ ob) {
    int p = blockIdx.x;                // [0, 2560)
    int x = p & 7, j = p >> 3;         // XCD, seq within XCD [0,320)
    int c = j >> 6, s = j & 63;        // 64-block cluster, slot
    int C = c * 8 + x;                 // [0,40)
    int mtg = C >> 1, byg = C & 1;     // mt-major: consecutive C share mtg
    int mt = mtg * 8 + (s >> 3);       // [0,160), padded
    int by = byg * 8 + (s & 7);        // [0,16)
    if (mt >= *nmt) return;
    const int e = mt_e[mt], row0 = mt_r0[mt];
    const int tid = threadIdx.x, lane = tid & 63, wv = tid >> 6;
    const int wm = wv >> 1, wn = wv & 1;

    __shared__ u16 sA[128 * 64];
    __shared__ u16 sB[128 * 64];

    const u16* asrc[4];
    const u16* bsrc[4];
#pragma unroll
    for (int i = 0; i < 4; ++i) {
        int rl = i * 32 + (tid >> 3);
        int kbs = ((tid & 7) * 16) ^ ((rl & 7) << 4);
        asrc[i] = hb + (size_t)(row0 >> 7) * (ID * 128) + rl * 64 + (kbs >> 1);
        bsrc[i] = w2t + (size_t)e * HD * ID + (size_t)by * (ID * 128) + rl * 64 + (kbs >> 1);
    }

    f32x4 acc[4][4];
#pragma unroll
    for (int a = 0; a < 4; ++a)
#pragma unroll
        for (int b = 0; b < 4; ++b) acc[a][b] = (f32x4)0.f;

    for (int kt = 0; kt < ID / 64; ++kt) {
#pragma unroll
        for (int i = 0; i < 4; ++i) {
            __builtin_amdgcn_global_load_lds(
                (const __attribute__((address_space(1))) void*)asrc[i],
                (__attribute__((address_space(3))) void*)(sA + i * 2048 + wv * 512), 16, 0, 0);
            asrc[i] += 8192;
        }
#pragma unroll
        for (int i = 0; i < 4; ++i) {
            __builtin_amdgcn_global_load_lds(
                (const __attribute__((address_space(1))) void*)bsrc[i],
                (__attribute__((address_space(3))) void*)(sB + i * 2048 + wv * 512), 16, 0, 0);
            bsrc[i] += 8192;
        }
        __syncthreads();
#pragma unroll
        for (int ks = 0; ks < 2; ++ks) {
            i32x4 a[4], b[4];
#pragma unroll
            for (int mf = 0; mf < 4; ++mf) {
                int rr = wm * 64 + mf * 16 + (lane & 15);
                int lb = ((lane >> 4) * 16 + ks * 64) ^ ((rr & 7) << 4);
                a[mf] = *(const i32x4*)((const char*)sA + rr * 128 + lb);
            }
#pragma unroll
            for (int nf = 0; nf < 4; ++nf) {
                int nn = wn * 64 + nf * 16 + (lane & 15);
                int lb = ((lane >> 4) * 16 + ks * 64) ^ ((nn & 7) << 4);
                b[nf] = *(const i32x4*)((const char*)sB + nn * 128 + lb);
            }
#pragma unroll
            for (int nf = 0; nf < 4; ++nf)
#pragma unroll
                for (int mf = 0; mf < 4; ++mf)
                    asm("v_mfma_f32_16x16x32_f16 %0, %1, %2, %0" : "+v"(acc[mf][nf]) : "v"(a[mf]), "v"(b[nf]));
        }
        __syncthreads();
    }

#pragma unroll
    for (int mf = 0; mf < 4; ++mf) {
#pragma unroll
        for (int j2 = 0; j2 < 4; ++j2) {
            int rr = row0 + wm * 64 + mf * 16 + (lane >> 4) * 4 + j2;
            int pt2 = pair_tok2[rr];
            float wt = pair_w[rr];
            if (pt2 >= 0) {
                u16* op = ob + (size_t)pt2 * HD + by * 128 + wn * 64 + (lane & 15);
#pragma unroll
                for (int nf = 0; nf < 4; ++nf) {
                    op[nf * 16] = f2h(acc[mf][nf][j2] * wt);
                }
            }
        }
    }
}

// ---------------- combine: out[t] = ob16[2t] + ob16[2t+1] ----------------
__global__ __launch_bounds__(256) void combine_kernel(const u16* __restrict__ ob,
                                                      float* __restrict__ out) {
    int t = blockIdx.x;
    const u16x8* r0 = (const u16x8*)(ob + (size_t)(2 * t) * HD);
    const u16x8* r1 = (const u16x8*)(ob + (size_t)(2 * t + 1) * HD);
    float* o = out + (size_t)t * HD;
    int i = threadIdx.x;      // 256 threads x 8 elems = 2048
    u16x8 a = r0[i], b = r1[i];
    f32x4 o0, o1;
#pragma unroll
    for (int k = 0; k < 4; ++k) {
        o0[k] = h2f(a[k]) + h2f(b[k]);
        o1[k] = h2f(a[4 + k]) + h2f(b[4 + k]);
    }
    ((f32x4*)(o + i * 8))[0] = o0;
    ((f32x4*)(o + i * 8))[1] = o1;
}

extern "C" void kernel_launch(void* const* d_in, const int* in_sizes, int n_in,
                              void* d_out, int out_size, void* d_ws, size_t ws_size,
                              hipStream_t stream) {
    (void)in_sizes; (void)n_in; (void)out_size;
    const float* x  = (const float*)d_in[0];
    const float* wg = (const float*)d_in[1];
    const float* w1 = (const float*)d_in[2];
    const float* w3 = (const float*)d_in[3];
    const float* w2 = (const float*)d_in[4];
    float* out = (float*)d_out;

    char* ws = (char*)d_ws;
    size_t off = 0;
    auto alloc = [&](size_t bytes) -> void* {
        void* p = ws + off;
        off = (off + bytes + 255) & ~(size_t)255;
        return p;
    };
    u16* xh          = (u16*)alloc((size_t)TOK * HD * 2);
    u16* hb          = (u16*)alloc((size_t)PPAD * ID * 2);
    u16* wcat        = (u16*)alloc((size_t)NE * 2 * ID * HD * 2);  // w13 fp16
    u16* ob          = wcat;   // fp16 ob [2*TOK][HD] aliases wcat (dead after gemm1)
    int* pair_tok2   = (int*)alloc((size_t)PPAD * 4);
    float* pair_w    = (float*)alloc((size_t)PPAD * 4);
    int* top_e       = (int*)alloc((size_t)TOK * 2 * 4);
    float* top_w     = (float*)alloc((size_t)TOK * 2 * 4);
    int* counts      = (int*)alloc(64);
    int* offs        = (int*)alloc(64);
    int* mt_e        = (int*)alloc((size_t)MAXMT * 4);
    int* mt_r0       = (int*)alloc((size_t)MAXMT * 4);
    int* nmt         = (int*)alloc(64);

    // planA: separate w2t -> prep_w2 fuses with gemm1 (runs concurrently).
    // planB (small ws): w2t aliases wcat 2nd half, prep_w2 runs after gemm1.
    size_t w2t_bytes = (size_t)NE * ID * HD * 2;
    bool planA = (off + w2t_bytes) <= ws_size;
    u16* w2t = planA ? (u16*)alloc(w2t_bytes)
                     : wcat + (size_t)NE * ID * HD;

    hipMemsetAsync(counts, 0, 64, stream);

    // router || prep_w13 (independent)
    fused1_kernel<<<RGRID + P13GRID, 256, 0, stream>>>(
        x, wg, xh, top_e, top_w, counts, w1, w3, wcat);
    // merged offsets + mt-tables + deterministic compaction (ballot scan)
    scatter_kernel<<<NE, 256, 0, stream>>>(top_e, top_w, counts, offs,
                                           mt_e, mt_r0, nmt, pair_tok2, pair_w);
    if (planA) {
        // gemm1 || prep_w2 (independent buffers)
        fused2_kernel<<<G1GRID + P2GRID, 256, 0, stream>>>(
            xh, wcat, pair_tok2, mt_e, mt_r0, nmt, hb, w2, w2t);
    } else {
        fused2_kernel<<<G1GRID, 256, 0, stream>>>(
            xh, wcat, pair_tok2, mt_e, mt_r0, nmt, hb, w2, w2t);
        prep_w2_kernel<<<dim3(ID / 64, HD / 64, NE), 256, 0, stream>>>(w2, w2t);
    }
    // gemm2: mt padded to 160 x 16 by, XCD-clustered (8mt x 8by clusters)
    gemm2_kernel<<<160 * (HD / 128), 256, 0, stream>>>(hb, w2t, pair_tok2, pair_w, mt_e, mt_r0, nmt, ob);
    combine_kernel<<<TOK, 256, 0, stream>>>(ob, out);
}